// Round 16
// baseline (390.446 us; speedup 1.0000x reference)
//
#include <hip/hip_runtime.h>
#include <math.h>
#include <stdint.h>

#define DEV_INLINE __device__ __forceinline__

constexpr int R_ = 256, C_ = 384, E_ = 384, H_ = 12, D_ = 32;
constexpr float NEGF = -3.402823466e38f;

typedef __attribute__((ext_vector_type(4))) float f32x4;
typedef __attribute__((ext_vector_type(8))) short short8;
typedef __attribute__((ext_vector_type(4))) unsigned short u16x4;

// ---------------- workspace layout ----------------
constexpr size_t o_qs     = 0;                                 // C*E f32 (qs)
constexpr size_t o_p      = o_qs + (size_t)C_ * E_;            // Pb bf16 overlay
constexpr size_t o_logits = o_p + (size_t)C_ * H_ * E_;        // swT f32 [12][256][384]
constexpr size_t o_sw     = o_logits + (size_t)C_ * H_ * R_;   // (free)
constexpr size_t o_attn   = o_sw + (size_t)C_ * H_ * R_;       // QKf0; Wtb overlays pre-qk
constexpr size_t o_q3     = o_attn + (size_t)H_ * C_ * C_;
constexpr size_t SZBIG  = 75497472;                  // bytes per big region
constexpr size_t ob_q3b = o_q3 * 4;                  // 24,182,784 (attnb overlays after qk)
constexpr size_t ob_k3b = ob_q3b + SZBIG;
constexpr size_t ob_v3b = ob_k3b + SZBIG;
constexpr size_t ob_xb  = ob_v3b + SZBIG;            // ends 326,172,672; QKf1/2/3 overlay after proj
constexpr size_t QKSZ   = 7077888;                   // H*C*C*4 bytes

// ---------------- helpers ----------------
DEV_INLINE unsigned short bf16h(float x) {
  unsigned int u = __builtin_bit_cast(unsigned int, x);
  unsigned int r = (u + 0x7FFFu + ((u >> 16) & 1u)) >> 16;
  return (unsigned short)r;
}
DEV_INLINE float waveRedMax(float v) {
#pragma unroll
  for (int o = 32; o > 0; o >>= 1) v = fmaxf(v, __shfl_down(v, o));
  return v;
}
DEV_INLINE float waveRedSum(float v) {
#pragma unroll
  for (int o = 32; o > 0; o >>= 1) v += __shfl_down(v, o);
  return v;
}

// ---------------- async global->LDS staging (linear LDS + swizzled source) ----------------
DEV_INLINE void gll16(const void* g, void* l) {
  __builtin_amdgcn_global_load_lds(
      reinterpret_cast<__attribute__((address_space(1))) void*>(
          reinterpret_cast<uintptr_t>(g)),
      reinterpret_cast<__attribute__((address_space(3))) void*>(
          reinterpret_cast<uintptr_t>(l)),
      16, 0, 0);
}

template <int ROWS, int UPR, int MASK, int SHIFT>
DEV_INLINE void stageT(const unsigned short* __restrict__ g, int lda,
                       unsigned short* l) {
  int t = threadIdx.x, w = t >> 6, lane = t & 63;
  constexpr int NI = (ROWS * UPR) / 64;
  constexpr int PW = NI / 4;
#pragma unroll
  for (int j = 0; j < PW; ++j) {
    int u0 = (w * PW + j) * 64;
    int u = u0 + lane;
    int row = u / UPR, qp = u % UPR;
    int q = qp ^ ((row >> SHIFT) & MASK);
    gll16(g + (size_t)row * lda + q * 8, l + (size_t)u0 * 8);
  }
}

template <int MASK, int SHIFT>
DEV_INLINE short8 fragLd(const unsigned short* base, int row, int q, int rowShorts) {
  int qp = q ^ ((row >> SHIFT) & MASK);
  return *(const short8*)(base + row * rowShorts + qp * 8);
}

// ================= stage 1 =================
__global__ void k_qs(const float* __restrict__ x, const float* __restrict__ Wq_s,
                     float* __restrict__ ws) {
  int c = blockIdx.x, t = threadIdx.x;
  __shared__ float xl[E_];
  xl[t] = x[(size_t)c * E_ + t];
  __syncthreads();
  float s = 0.f;
#pragma unroll 8
  for (int k = 0; k < E_; ++k) s += xl[k] * Wq_s[(size_t)k * E_ + t];
  ws[o_qs + (size_t)c * E_ + t] = s * 0.17677669529663687f;
}

__global__ void k_p(const float* __restrict__ Wk_s, const float* __restrict__ ws,
                    unsigned short* __restrict__ Pb) {
  int h = blockIdx.x, c = blockIdx.y, t = threadIdx.x;
  __shared__ float q[D_];
  float s = 0.f;
  if (h < 12) {
    if (t < D_) q[t] = ws[o_qs + (size_t)c * E_ + h * D_ + t];
    __syncthreads();
    const float* wrow = &Wk_s[(size_t)t * E_ + h * D_];
#pragma unroll
    for (int d = 0; d < D_; d += 4) {
      float4 w = *(const float4*)&wrow[d];
      s += w.x * q[d] + w.y * q[d + 1] + w.z * q[d + 2] + w.w * q[d + 3];
    }
  }
  Pb[((size_t)c * 16 + h) * 384 + t] = bf16h(s);
}

// ---------------- fused logits + softmax_r -> swT[h][r][c] ----------------
__global__ __launch_bounds__(256) void k_logits_sm(
    const unsigned short* __restrict__ xb, const unsigned short* __restrict__ Pb,
    const int* __restrict__ seq_mask, float* __restrict__ swT) {
  int c = blockIdx.x, t = threadIdx.x;
  __shared__ unsigned short sA[256 * 32];
  __shared__ unsigned short sB[16 * 32];
  __shared__ float lg[12 * 256];
  __shared__ float red[4];
  int w = t >> 6, lane = t & 63, id16 = lane & 15, g = lane >> 4;
  f32x4 acc[4];
#pragma unroll
  for (int mi = 0; mi < 4; ++mi) acc[mi] = (f32x4){0.f, 0.f, 0.f, 0.f};

  for (int k0 = 0; k0 < 384; k0 += 32) {
    stageT<256, 4, 3, 0>(xb + (size_t)c * 384 + k0, 384 * 384, sA);
    if (w == 0) {
      int row = lane >> 2, qp = lane & 3, q = qp ^ (row & 3);
      gll16(Pb + ((size_t)c * 16 + row) * 384 + k0 + q * 8, sB);
    }
    __syncthreads();
    short8 Bf = fragLd<3, 0>(sB, id16, g, 32);
#pragma unroll
    for (int mi = 0; mi < 4; ++mi) {
      short8 Af = fragLd<3, 0>(sA, w * 64 + mi * 16 + id16, g, 32);
      acc[mi] = __builtin_amdgcn_mfma_f32_16x16x32_bf16(Af, Bf, acc[mi], 0, 0, 0);
    }
    __syncthreads();
  }
  int l4 = (lane >> 4) * 4;
#pragma unroll
  for (int mi = 0; mi < 4; ++mi) {
    if (id16 < 12) {
      f32x4 a = acc[mi];
#pragma unroll
      for (int reg = 0; reg < 4; ++reg)
        lg[id16 * 256 + w * 64 + mi * 16 + l4 + reg] = a[reg];
    }
  }
  __syncthreads();
  int wid = t >> 6;
  const float scal = 0.17677669529663687f / sqrtf((float)C_);
  bool masked = (seq_mask[t] == 0);
  for (int h = 0; h < 12; ++h) {
    float v = masked ? NEGF : lg[h * 256 + t];
    float m = waveRedMax(v);
    if ((t & 63) == 0) red[wid] = m;
    __syncthreads();
    float mx = fmaxf(fmaxf(red[0], red[1]), fmaxf(red[2], red[3]));
    __syncthreads();
    float e = expf(v - mx);
    float s = waveRedSum(e);
    if ((t & 63) == 0) red[wid] = s;
    __syncthreads();
    float sum = red[0] + red[1] + red[2] + red[3];
    swT[((size_t)h * 256 + t) * 384 + c] = e / sum * scal;
    __syncthreads();
  }
}

// ---------------- conversions ----------------
__global__ void k_cvt_x(const float* __restrict__ x, unsigned short* __restrict__ xb) {
  size_t i = ((size_t)blockIdx.x * 256 + threadIdx.x) * 16;
  unsigned short h[16];
#pragma unroll
  for (int j = 0; j < 4; ++j) {
    float4 f = *(const float4*)&x[i + j * 4];
    h[j * 4 + 0] = bf16h(f.x);
    h[j * 4 + 1] = bf16h(f.y);
    h[j * 4 + 2] = bf16h(f.z);
    h[j * 4 + 3] = bf16h(f.w);
  }
  *(short8*)&xb[i] = *(const short8*)&h[0];
  *(short8*)&xb[i + 8] = *(const short8*)&h[8];
}

__global__ void k_cvt_w(const float* __restrict__ Wq, const float* __restrict__ Wk,
                        const float* __restrict__ Wv, unsigned short* __restrict__ Wtb) {
  int n = blockIdx.x, k = threadIdx.x;
  const float* W;
  int col;
  if (n < 384)      { W = Wq; col = n; }
  else if (n < 768) { W = Wk; col = n - 384; }
  else              { W = Wv; col = n - 768; }
  Wtb[(size_t)n * 384 + k] = bf16h(W[(size_t)k * 384 + col]);
}

// ---------------- k_proj_all: 128x128 tile, BK=32 DOUBLE-BUFFERED (T3-min) ----------------
__global__ __launch_bounds__(256, 4) void k_proj_all(
    const unsigned short* __restrict__ xb, const unsigned short* __restrict__ Wtb,
    const float* __restrict__ swT, unsigned short* __restrict__ Q3b,
    unsigned short* __restrict__ K3b, unsigned short* __restrict__ V3b) {
  __shared__ __align__(16) unsigned short smem[16384];  // 32KB: sA0|sA1|sB0|sB1; epi reuse
  unsigned short* sAb[2] = {smem, smem + 4096};
  unsigned short* sBb[2] = {smem + 8192, smem + 12288};
  int Dd = blockIdx.x;                       // 6912 blocks; /8 = 864 -> bijective
  int L = (Dd & 7) * 864 + (Dd >> 3);
  int bm = L / 9, bn = L - bm * 9;
  int n0 = bn * 128, m0 = bm * 128;
  int wave = threadIdx.x >> 6, wr = wave >> 1, wc = wave & 1;
  int lane = threadIdx.x & 63, id16 = lane & 15, g = lane >> 4;
  f32x4 acc[4][4];
#pragma unroll
  for (int mi = 0; mi < 4; ++mi)
#pragma unroll
    for (int ni = 0; ni < 4; ++ni) acc[mi][ni] = (f32x4){0.f, 0.f, 0.f, 0.f};

  stageT<128, 4, 3, 1>(xb + (size_t)m0 * 384, 384, sAb[0]);
  stageT<128, 4, 3, 1>(Wtb + (size_t)n0 * 384, 384, sBb[0]);
  __syncthreads();
  for (int it = 0; it < 12; ++it) {
    int cur = it & 1;
    if (it < 11) {
      stageT<128, 4, 3, 1>(xb + (size_t)m0 * 384 + (it + 1) * 32, 384, sAb[cur ^ 1]);
      stageT<128, 4, 3, 1>(Wtb + (size_t)n0 * 384 + (it + 1) * 32, 384, sBb[cur ^ 1]);
    }
    short8 Af[4], Bf[4];
#pragma unroll
    for (int mi = 0; mi < 4; ++mi)
      Af[mi] = fragLd<3, 1>(sAb[cur], wr * 64 + mi * 16 + id16, g, 32);
#pragma unroll
    for (int ni = 0; ni < 4; ++ni)
      Bf[ni] = fragLd<3, 1>(sBb[cur], wc * 64 + ni * 16 + id16, g, 32);
#pragma unroll
    for (int mi = 0; mi < 4; ++mi)
#pragma unroll
      for (int ni = 0; ni < 4; ++ni)
        acc[mi][ni] = __builtin_amdgcn_mfma_f32_16x16x32_bf16(Af[mi], Bf[ni],
                                                              acc[mi][ni], 0, 0, 0);
    __syncthreads();
  }

  int l4 = (lane >> 4) * 4;
  int r = bm / 3, cb = (bm % 3) * 128;
  if (bn < 6) {
    bool isQ = bn < 3;
    int hbase = isQ ? bn * 4 : (bn - 3) * 4;
#pragma unroll
    for (int mi = 0; mi < 4; ++mi) {
      int clBase = wr * 64 + mi * 16 + l4;
#pragma unroll
      for (int ni = 0; ni < 4; ++ni) {
        int nl = wc * 64 + ni * 16 + id16;
        int hhl = nl >> 5, d = nl & 31;
        f32x4 a = acc[mi][ni];
        if (isQ) {
          float4 sv =
              *(const float4*)&swT[((size_t)(hbase + hhl) * 256 + r) * 384 + cb + clBase];
          a[0] *= sv.x; a[1] *= sv.y; a[2] *= sv.z; a[3] *= sv.w;
        }
#pragma unroll
        for (int reg = 0; reg < 4; ++reg)
          smem[hhl * 4096 + (clBase + reg) * 32 + d] = bf16h(a[reg]);
      }
    }
    __syncthreads();
    unsigned short* dst = isQ ? Q3b : K3b;
#pragma unroll
    for (int seg = 0; seg < 8; ++seg) {
      int off = seg * 2048 + threadIdx.x * 8;
      int hhl = off >> 12, inner = off & 4095;
      int hg = hbase + hhl;
      *(short8*)(dst + (((size_t)hg * 256 + r) * 384 + cb) * 32 + inner) =
          *(const short8*)(smem + off);
    }
  } else {  // V: V3b[h][r*32+d][c]
#pragma unroll
    for (int mi = 0; mi < 4; ++mi) {
      int c0 = cb + wr * 64 + mi * 16 + l4;
#pragma unroll
      for (int ni = 0; ni < 4; ++ni) {
        int nv = n0 + wc * 64 + ni * 16 + id16 - 768;
        int hh = nv >> 5, dd = nv & 31;
        f32x4 a = acc[mi][ni];
        u16x4 hv;
#pragma unroll
        for (int reg = 0; reg < 4; ++reg) hv[reg] = bf16h(a[reg]);
        *(u16x4*)(V3b + ((size_t)hh * 8192 + r * 32 + dd) * 384 + c0) = hv;
      }
    }
  }
}

// ---------------- k_qk_mma: 128x128 tiles, split-K x4, per-slice double buffer ----------------
__global__ __launch_bounds__(256, 4) void k_qk_mma(
    const unsigned short* __restrict__ Q3b, const unsigned short* __restrict__ K3b,
    float* __restrict__ QKf0, float* __restrict__ QKf1,
    float* __restrict__ QKf2, float* __restrict__ QKf3) {
  __shared__ unsigned short sA[2][4096], sB[2][4096];  // 32KB
  int Dd = blockIdx.x;                       // 432 blocks; /8 = 54 -> bijective
  int L = (Dd & 7) * 54 + (Dd >> 3);
  int kh = L / 108, rem = L - kh * 108;
  int h = rem / 9, r2 = rem - h * 9, bi = r2 / 3, bj = r2 - bi * 3;
  int i0 = bi * 128, j0 = bj * 128;
  int wave = threadIdx.x >> 6, wr = wave >> 1, wc = wave & 1;
  int lane = threadIdx.x & 63, id16 = lane & 15, g = lane >> 4;
  f32x4 acc[4][4];
#pragma unroll
  for (int mi = 0; mi < 4; ++mi)
#pragma unroll
    for (int ni = 0; ni < 4; ++ni) acc[mi][ni] = (f32x4){0.f, 0.f, 0.f, 0.f};
  int rbase = kh * 64;

  stageT<128, 4, 3, 1>(Q3b + (((size_t)h * 256 + rbase) * 384 + i0) * 32, 32, sA[0]);
  stageT<128, 4, 3, 1>(K3b + (((size_t)h * 256 + rbase) * 384 + j0) * 32, 32, sB[0]);
  __syncthreads();
  for (int it = 0; it < 64; ++it) {
    int cur = it & 1;
    if (it < 63) {
      int r = rbase + it + 1;
      stageT<128, 4, 3, 1>(Q3b + (((size_t)h * 256 + r) * 384 + i0) * 32, 32,
                           sA[cur ^ 1]);
      stageT<128, 4, 3, 1>(K3b + (((size_t)h * 256 + r) * 384 + j0) * 32, 32,
                           sB[cur ^ 1]);
    }
    short8 Af[4], Bf[4];
#pragma unroll
    for (int mi = 0; mi < 4; ++mi)
      Af[mi] = fragLd<3, 1>(sA[cur], wr * 64 + mi * 16 + id16, g, 32);
#pragma unroll
    for (int ni = 0; ni < 4; ++ni)
      Bf[ni] = fragLd<3, 1>(sB[cur], wc * 64 + ni * 16 + id16, g, 32);
#pragma unroll
    for (int mi = 0; mi < 4; ++mi)
#pragma unroll
      for (int ni = 0; ni < 4; ++ni)
        acc[mi][ni] = __builtin_amdgcn_mfma_f32_16x16x32_bf16(Af[mi], Bf[ni],
                                                              acc[mi][ni], 0, 0, 0);
    __syncthreads();
  }
  int l4 = (lane >> 4) * 4;
  float* dst = (kh == 0) ? QKf0 : (kh == 1) ? QKf1 : (kh == 2) ? QKf2 : QKf3;
#pragma unroll
  for (int mi = 0; mi < 4; ++mi)
#pragma unroll
    for (int ni = 0; ni < 4; ++ni) {
      int ii = i0 + wr * 64 + mi * 16 + l4;
      int j = j0 + wc * 64 + ni * 16 + id16;
      f32x4 a = acc[mi][ni];
#pragma unroll
      for (int reg = 0; reg < 4; ++reg)
        dst[((size_t)h * 384 + ii + reg) * 384 + j] = a[reg];
    }
}

// ---------------- k_softmax_j: sum 4 split-K partials, softmax, emit bf16 ----------------
__global__ void k_softmax_j(const int* __restrict__ res_mask, const float* __restrict__ QKf0,
                            const float* __restrict__ QKf1, const float* __restrict__ QKf2,
                            const float* __restrict__ QKf3,
                            unsigned short* __restrict__ attnb) {
  int i = blockIdx.x, h = blockIdx.y, t = threadIdx.x;
  int lane = t & 63, wid = t >> 6;
  size_t base = ((size_t)h * C_ + i) * C_;
  float v = (QKf0[base + t] + QKf1[base + t]) + (QKf2[base + t] + QKf3[base + t]);
  if ((res_mask[i] * res_mask[t]) == 0) v = NEGF;
  __shared__ float red[6];
  float m = waveRedMax(v);
  if (lane == 0) red[wid] = m;
  __syncthreads();
  float mx = red[0];
#pragma unroll
  for (int w = 1; w < 6; ++w) mx = fmaxf(mx, red[w]);
  __syncthreads();
  float e = expf(v - mx);
  float s = waveRedSum(e);
  if (lane == 0) red[wid] = s;
  __syncthreads();
  float sum = 0.f;
#pragma unroll
  for (int w = 0; w < 6; ++w) sum += red[w];
  attnb[base + t] = bf16h(e / sum);
}

// ---------------- k_out_mma: 128x128 tile, BK=32 double-buffered, f32 LDS epilogue ----------------
__global__ __launch_bounds__(256, 4) void k_out_mma(
    const unsigned short* __restrict__ attnb, const unsigned short* __restrict__ V3b,
    float* __restrict__ out) {
  __shared__ __align__(16) unsigned short smem[16384];  // 32KB; epi reuse as f32
  unsigned short* sAb[2] = {smem, smem + 4096};
  unsigned short* sBb[2] = {smem + 8192, smem + 12288};
  int Dd = blockIdx.x;                        // 2304 blocks; /8 = 288 -> bijective
  int L = (Dd & 7) * 288 + (Dd >> 3);
  int bn = L % 64, bm = (L / 64) % 3, h = L / 192;
  int n0 = bn * 128, m0 = bm * 128;
  int wave = threadIdx.x >> 6, wr = wave >> 1, wc = wave & 1;
  int lane = threadIdx.x & 63, id16 = lane & 15, g = lane >> 4;
  f32x4 acc[4][4];
#pragma unroll
  for (int mi = 0; mi < 4; ++mi)
#pragma unroll
    for (int ni = 0; ni < 4; ++ni) acc[mi][ni] = (f32x4){0.f, 0.f, 0.f, 0.f};
  const unsigned short* Ab = attnb + (size_t)h * 384 * 384 + (size_t)m0 * 384;
  const unsigned short* Bb = V3b + (size_t)h * 8192 * 384 + (size_t)n0 * 384;

  stageT<128, 4, 3, 1>(Ab, 384, sAb[0]);
  stageT<128, 4, 3, 1>(Bb, 384, sBb[0]);
  __syncthreads();
  for (int it = 0; it < 12; ++it) {
    int cur = it & 1;
    if (it < 11) {
      stageT<128, 4, 3, 1>(Ab + (it + 1) * 32, 384, sAb[cur ^ 1]);
      stageT<128, 4, 3, 1>(Bb + (it + 1) * 32, 384, sBb[cur ^ 1]);
    }
    short8 Af[4], Bf[4];
#pragma unroll
    for (int mi = 0; mi < 4; ++mi)
      Af[mi] = fragLd<3, 1>(sAb[cur], wr * 64 + mi * 16 + id16, g, 32);
#pragma unroll
    for (int ni = 0; ni < 4; ++ni)
      Bf[ni] = fragLd<3, 1>(sBb[cur], wc * 64 + ni * 16 + id16, g, 32);
#pragma unroll
    for (int mi = 0; mi < 4; ++mi)
#pragma unroll
      for (int ni = 0; ni < 4; ++ni)
        acc[mi][ni] = __builtin_amdgcn_mfma_f32_16x16x32_bf16(Af[mi], Bf[ni],
                                                              acc[mi][ni], 0, 0, 0);
    __syncthreads();
  }

  // Epilogue: two passes; stage [plane(wc) 2][i 128][d 32] f32 in LDS, write float4.
  int l4 = (lane >> 4) * 4;
  float* smf = (float*)smem;
#pragma unroll
  for (int p = 0; p < 2; ++p) {
#pragma unroll
    for (int mi = 0; mi < 4; ++mi) {
      int iL = wr * 64 + mi * 16 + l4;
#pragma unroll
      for (int nq = 0; nq < 2; ++nq) {
        int ni = 2 * p + nq;
        int d = nq * 16 + id16;
        f32x4 a = acc[mi][ni];
#pragma unroll
        for (int reg = 0; reg < 4; ++reg)
          smf[wc * 4096 + (iL + reg) * 32 + d] = a[reg];
      }
    }
    __syncthreads();
#pragma unroll
    for (int seg = 0; seg < 8; ++seg) {
      int o = seg * 1024 + threadIdx.x * 4;
      int plane = o >> 12, rest = o & 4095;
      int iL = rest >> 5, d = rest & 31;
      int rg = (n0 >> 5) + plane * 2 + p;
      *(float4*)&out[(((size_t)rg * 384 + m0 + iL) * 12 + h) * 32 + d] =
          *(const float4*)&smf[o];
    }
    __syncthreads();
  }
}

extern "C" void kernel_launch(void* const* d_in, const int* in_sizes, int n_in,
                              void* d_out, int out_size, void* d_ws, size_t ws_size,
                              hipStream_t stream) {
  const float* x = (const float*)d_in[0];
  const float* Wq = (const float*)d_in[1];
  const float* Wk = (const float*)d_in[2];
  const float* Wv = (const float*)d_in[3];
  const float* Wq_s = (const float*)d_in[4];
  const float* Wk_s = (const float*)d_in[5];
  const int* res_mask = (const int*)d_in[6];
  const int* seq_mask = (const int*)d_in[7];
  float* ws = (float*)d_ws;
  char* wsb = (char*)d_ws;
  float* out = (float*)d_out;

  unsigned short* Pb  = (unsigned short*)(wsb + o_p * 4);
  float* swT          = ws + o_logits;
  unsigned short* Wtb = (unsigned short*)(wsb + o_attn * 4);
  float* QKf0         = ws + o_attn;
  unsigned short* Q3b = (unsigned short*)(wsb + ob_q3b);
  unsigned short* K3b = (unsigned short*)(wsb + ob_k3b);
  unsigned short* V3b = (unsigned short*)(wsb + ob_v3b);
  unsigned short* xb  = (unsigned short*)(wsb + ob_xb);
  unsigned short* attnb = Q3b;
  float* QKf1 = (float*)(wsb + ob_xb);
  float* QKf2 = (float*)(wsb + ob_xb + QKSZ);
  float* QKf3 = (float*)(wsb + ob_xb + 2 * QKSZ);

  hipLaunchKernelGGL(k_cvt_x, dim3(9216), dim3(256), 0, stream, x, xb);
  hipLaunchKernelGGL(k_qs, dim3(C_), dim3(E_), 0, stream, x, Wq_s, ws);
  hipLaunchKernelGGL(k_p, dim3(16, C_), dim3(E_), 0, stream, Wk_s, ws, Pb);
  hipLaunchKernelGGL(k_logits_sm, dim3(C_), dim3(256), 0, stream, xb, Pb, seq_mask, swT);
  hipLaunchKernelGGL(k_cvt_w, dim3(1152), dim3(384), 0, stream, Wq, Wk, Wv, Wtb);
  hipLaunchKernelGGL(k_proj_all, dim3(6912), dim3(256), 0, stream, xb, Wtb, swT,
                     Q3b, K3b, V3b);
  hipLaunchKernelGGL(k_qk_mma, dim3(432), dim3(256), 0, stream, Q3b, K3b,
                     QKf0, QKf1, QKf2, QKf3);
  hipLaunchKernelGGL(k_softmax_j, dim3(C_, H_), dim3(C_), 0, stream, res_mask,
                     QKf0, QKf1, QKf2, QKf3, attnb);
  hipLaunchKernelGGL(k_out_mma, dim3(2304), dim3(256), 0, stream, attnb, V3b, out);
}

// Round 17
// 358.487 us; speedup vs baseline: 1.0891x; 1.0891x over previous
//
#include <hip/hip_runtime.h>
#include <math.h>
#include <stdint.h>

#define DEV_INLINE __device__ __forceinline__

constexpr int R_ = 256, C_ = 384, E_ = 384, H_ = 12, D_ = 32;
constexpr float NEGF = -3.402823466e38f;

typedef __attribute__((ext_vector_type(4))) float f32x4;
typedef __attribute__((ext_vector_type(8))) short short8;
typedef __attribute__((ext_vector_type(4))) unsigned short u16x4;

// ---------------- workspace layout ----------------
constexpr size_t o_qs     = 0;                                 // (free)
constexpr size_t o_p      = o_qs + (size_t)C_ * E_;            // (free)
constexpr size_t o_logits = o_p + (size_t)C_ * H_ * E_;        // swT f32 [12][256][384]
constexpr size_t o_sw     = o_logits + (size_t)C_ * H_ * R_;   // (free)
constexpr size_t o_attn   = o_sw + (size_t)C_ * H_ * R_;       // QKf0; Wtb overlays pre-qk
constexpr size_t o_q3     = o_attn + (size_t)H_ * C_ * C_;
constexpr size_t SZBIG  = 75497472;                  // bytes per big region
constexpr size_t ob_q3b = o_q3 * 4;                  // 24,182,784 (attnb overlays after qk)
constexpr size_t ob_k3b = ob_q3b + SZBIG;
constexpr size_t ob_v3b = ob_k3b + SZBIG;
constexpr size_t ob_xb  = ob_v3b + SZBIG;            // ends 326,172,672; QKf1/2/3 overlay after proj
constexpr size_t QKSZ   = 7077888;                   // H*C*C*4 bytes

// ---------------- helpers ----------------
DEV_INLINE unsigned short bf16h(float x) {
  unsigned int u = __builtin_bit_cast(unsigned int, x);
  unsigned int r = (u + 0x7FFFu + ((u >> 16) & 1u)) >> 16;
  return (unsigned short)r;
}
DEV_INLINE float waveRedMax(float v) {
#pragma unroll
  for (int o = 32; o > 0; o >>= 1) v = fmaxf(v, __shfl_down(v, o));
  return v;
}
DEV_INLINE float waveRedSum(float v) {
#pragma unroll
  for (int o = 32; o > 0; o >>= 1) v += __shfl_down(v, o);
  return v;
}

// ---------------- async global->LDS staging (linear LDS + swizzled source) ----------------
DEV_INLINE void gll16(const void* g, void* l) {
  __builtin_amdgcn_global_load_lds(
      reinterpret_cast<__attribute__((address_space(1))) void*>(
          reinterpret_cast<uintptr_t>(g)),
      reinterpret_cast<__attribute__((address_space(3))) void*>(
          reinterpret_cast<uintptr_t>(l)),
      16, 0, 0);
}

template <int ROWS, int UPR, int MASK, int SHIFT>
DEV_INLINE void stageT(const unsigned short* __restrict__ g, int lda,
                       unsigned short* l) {
  int t = threadIdx.x, w = t >> 6, lane = t & 63;
  constexpr int NI = (ROWS * UPR) / 64;
  constexpr int PW = NI / 4;
#pragma unroll
  for (int j = 0; j < PW; ++j) {
    int u0 = (w * PW + j) * 64;
    int u = u0 + lane;
    int row = u / UPR, qp = u % UPR;
    int q = qp ^ ((row >> SHIFT) & MASK);
    gll16(g + (size_t)row * lda + q * 8, l + (size_t)u0 * 8);
  }
}

template <int MASK, int SHIFT>
DEV_INLINE short8 fragLd(const unsigned short* base, int row, int q, int rowShorts) {
  int qp = q ^ ((row >> SHIFT) & MASK);
  return *(const short8*)(base + row * rowShorts + qp * 8);
}

// ================= k_prep: cvt_x + cvt_w fused (384 threads) =================
__global__ void k_prep(const float* __restrict__ x, const float* __restrict__ Wq,
                       const float* __restrict__ Wk, const float* __restrict__ Wv,
                       unsigned short* __restrict__ xb, unsigned short* __restrict__ Wtb) {
  int bid = blockIdx.x, t = threadIdx.x;
  if (bid < 6144) {  // cvt_x
    size_t i = ((size_t)bid * 384 + t) * 16;
    unsigned short h[16];
#pragma unroll
    for (int j = 0; j < 4; ++j) {
      float4 f = *(const float4*)&x[i + j * 4];
      h[j * 4 + 0] = bf16h(f.x);
      h[j * 4 + 1] = bf16h(f.y);
      h[j * 4 + 2] = bf16h(f.z);
      h[j * 4 + 3] = bf16h(f.w);
    }
    *(short8*)&xb[i] = *(const short8*)&h[0];
    *(short8*)&xb[i + 8] = *(const short8*)&h[8];
  } else {  // cvt_w
    int n = bid - 6144;
    const float* W;
    int col;
    if (n < 384)      { W = Wq; col = n; }
    else if (n < 768) { W = Wk; col = n - 384; }
    else              { W = Wv; col = n - 768; }
    Wtb[(size_t)n * 384 + t] = bf16h(W[(size_t)t * 384 + col]);
  }
}

// ---------------- fused qs + p + logits + softmax_r -> swT[h][r][c] ----------------
__global__ __launch_bounds__(256) void k_logits_sm(
    const float* __restrict__ x, const unsigned short* __restrict__ xb,
    const float* __restrict__ Wq_s, const float* __restrict__ Wk_s,
    const int* __restrict__ seq_mask, float* __restrict__ swT) {
  int c = blockIdx.x, t = threadIdx.x;
  __shared__ float xq[384], qs_l[384];
  __shared__ unsigned short pB[16 * 392];  // padded: 2-way bank reads
  __shared__ unsigned short sA[256 * 32];
  __shared__ float lg[12 * 256];
  __shared__ float red[4];
  int w = t >> 6, lane = t & 63, id16 = lane & 15, g = lane >> 4;

  // qs[c,:] = x[0,c,:] @ Wq_s * (1/sqrt(32))
  for (int k = t; k < 384; k += 256) xq[k] = x[(size_t)c * 384 + k];
  __syncthreads();
  for (int e = t; e < 384; e += 256) {
    float s = 0.f;
    for (int k = 0; k < 384; ++k) s += xq[k] * Wq_s[(size_t)k * 384 + e];
    qs_l[e] = s * 0.17677669529663687f;
  }
  __syncthreads();
  // p[h,kk] = sum_d Wk_s[kk, h*32+d] * qs[h*32+d] -> bf16 in pB
  for (int idx = t; idx < 4608; idx += 256) {
    int h = idx / 384, kk = idx - h * 384;
    const float* wrow = &Wk_s[(size_t)kk * 384 + h * 32];
    const float* qv = &qs_l[h * 32];
    float s = 0.f;
#pragma unroll
    for (int d = 0; d < 32; d += 4) {
      float4 wv = *(const float4*)&wrow[d];
      s += wv.x * qv[d] + wv.y * qv[d + 1] + wv.z * qv[d + 2] + wv.w * qv[d + 3];
    }
    pB[h * 392 + kk] = bf16h(s);
  }
  for (int i = t + 12 * 392; i < 16 * 392; i += 256) pB[i] = 0;
  __syncthreads();

  f32x4 acc[4];
#pragma unroll
  for (int mi = 0; mi < 4; ++mi) acc[mi] = (f32x4){0.f, 0.f, 0.f, 0.f};
  for (int k0 = 0; k0 < 384; k0 += 32) {
    stageT<256, 4, 3, 0>(xb + (size_t)c * 384 + k0, 384 * 384, sA);
    __syncthreads();
    short8 Bf = *(const short8*)(pB + id16 * 392 + k0 + g * 8);
#pragma unroll
    for (int mi = 0; mi < 4; ++mi) {
      short8 Af = fragLd<3, 0>(sA, w * 64 + mi * 16 + id16, g, 32);
      acc[mi] = __builtin_amdgcn_mfma_f32_16x16x32_bf16(Af, Bf, acc[mi], 0, 0, 0);
    }
    __syncthreads();
  }
  int l4 = (lane >> 4) * 4;
#pragma unroll
  for (int mi = 0; mi < 4; ++mi) {
    if (id16 < 12) {
      f32x4 a = acc[mi];
#pragma unroll
      for (int reg = 0; reg < 4; ++reg)
        lg[id16 * 256 + w * 64 + mi * 16 + l4 + reg] = a[reg];
    }
  }
  __syncthreads();
  int wid = t >> 6;
  const float scal = 0.17677669529663687f / sqrtf((float)C_);
  bool masked = (seq_mask[t] == 0);
  for (int h = 0; h < 12; ++h) {
    float v = masked ? NEGF : lg[h * 256 + t];
    float m = waveRedMax(v);
    if ((t & 63) == 0) red[wid] = m;
    __syncthreads();
    float mx = fmaxf(fmaxf(red[0], red[1]), fmaxf(red[2], red[3]));
    __syncthreads();
    float e = expf(v - mx);
    float s = waveRedSum(e);
    if ((t & 63) == 0) red[wid] = s;
    __syncthreads();
    float sum = red[0] + red[1] + red[2] + red[3];
    swT[((size_t)h * 256 + t) * 384 + c] = e / sum * scal;
    __syncthreads();
  }
}

// ---------------- k_proj_all: R15 main loop (BK=64 single-buffer) + V LDS epilogue ----------------
__global__ __launch_bounds__(256, 4) void k_proj_all(
    const unsigned short* __restrict__ xb, const unsigned short* __restrict__ Wtb,
    const float* __restrict__ swT, unsigned short* __restrict__ Q3b,
    unsigned short* __restrict__ K3b, unsigned short* __restrict__ V3b) {
  __shared__ __align__(16) unsigned short smem[2 * 128 * 64];  // 32KB; epi reuse
  unsigned short* sA = smem;
  unsigned short* sB = smem + 128 * 64;
  int Dd = blockIdx.x;                       // 6912 blocks; /8 = 864 -> bijective
  int L = (Dd & 7) * 864 + (Dd >> 3);
  int bm = L / 9, bn = L - bm * 9;
  int n0 = bn * 128, m0 = bm * 128;
  int wave = threadIdx.x >> 6, wr = wave >> 1, wc = wave & 1;
  int lane = threadIdx.x & 63, id16 = lane & 15, g = lane >> 4;
  f32x4 acc[4][4];
#pragma unroll
  for (int mi = 0; mi < 4; ++mi)
#pragma unroll
    for (int ni = 0; ni < 4; ++ni) acc[mi][ni] = (f32x4){0.f, 0.f, 0.f, 0.f};

  for (int it = 0; it < 6; ++it) {
    stageT<128, 8, 7, 0>(xb + (size_t)m0 * 384 + it * 64, 384, sA);
    stageT<128, 8, 7, 0>(Wtb + (size_t)n0 * 384 + it * 64, 384, sB);
    __syncthreads();
    short8 Af[4][2], Bf[4][2];
#pragma unroll
    for (int mi = 0; mi < 4; ++mi) {
      int row = wr * 64 + mi * 16 + id16;
#pragma unroll
      for (int kk = 0; kk < 2; ++kk) Af[mi][kk] = fragLd<7, 0>(sA, row, kk * 4 + g, 64);
    }
#pragma unroll
    for (int ni = 0; ni < 4; ++ni) {
      int col = wc * 64 + ni * 16 + id16;
#pragma unroll
      for (int kk = 0; kk < 2; ++kk) Bf[ni][kk] = fragLd<7, 0>(sB, col, kk * 4 + g, 64);
    }
#pragma unroll
    for (int kk = 0; kk < 2; ++kk)
#pragma unroll
      for (int mi = 0; mi < 4; ++mi)
#pragma unroll
        for (int ni = 0; ni < 4; ++ni)
          acc[mi][ni] = __builtin_amdgcn_mfma_f32_16x16x32_bf16(Af[mi][kk], Bf[ni][kk],
                                                                acc[mi][ni], 0, 0, 0);
    __syncthreads();
  }

  int l4 = (lane >> 4) * 4;
  int r = bm / 3, cb = (bm % 3) * 128;
  if (bn < 6) {
    bool isQ = bn < 3;
    int hbase = isQ ? bn * 4 : (bn - 3) * 4;
#pragma unroll
    for (int mi = 0; mi < 4; ++mi) {
      int clBase = wr * 64 + mi * 16 + l4;
#pragma unroll
      for (int ni = 0; ni < 4; ++ni) {
        int nl = wc * 64 + ni * 16 + id16;
        int hhl = nl >> 5, d = nl & 31;
        f32x4 a = acc[mi][ni];
        if (isQ) {
          float4 sv =
              *(const float4*)&swT[((size_t)(hbase + hhl) * 256 + r) * 384 + cb + clBase];
          a[0] *= sv.x; a[1] *= sv.y; a[2] *= sv.z; a[3] *= sv.w;
        }
#pragma unroll
        for (int reg = 0; reg < 4; ++reg)
          smem[hhl * 4096 + (clBase + reg) * 32 + d] = bf16h(a[reg]);
      }
    }
    __syncthreads();
    unsigned short* dst = isQ ? Q3b : K3b;
#pragma unroll
    for (int seg = 0; seg < 8; ++seg) {
      int off = seg * 2048 + threadIdx.x * 8;
      int hhl = off >> 12, inner = off & 4095;
      int hg = hbase + hhl;
      *(short8*)(dst + (((size_t)hg * 256 + r) * 384 + cb) * 32 + inner) =
          *(const short8*)(smem + off);
    }
  } else {  // V: LDS transpose epilogue -> V3b[h][r*32+d][c] coalesced
    int hbase = (bn - 6) * 4;
#pragma unroll
    for (int mi = 0; mi < 4; ++mi) {
      int clBase = wr * 64 + mi * 16 + l4;
#pragma unroll
      for (int ni = 0; ni < 4; ++ni) {
        int nl = wc * 64 + ni * 16 + id16;
        int hhl = nl >> 5, d = nl & 31;
        int cg = clBase ^ ((d & 7) << 2);  // 4-group XOR swizzle
        f32x4 a = acc[mi][ni];
        u16x4 hv;
#pragma unroll
        for (int reg = 0; reg < 4; ++reg) hv[reg] = bf16h(a[reg]);
        *(u16x4*)(smem + hhl * 4096 + d * 128 + cg) = hv;
      }
    }
    __syncthreads();
#pragma unroll
    for (int seg = 0; seg < 16; ++seg) {
      int Lg = seg * 1024 + threadIdx.x * 4;  // logical short idx
      int hhl = Lg >> 12, rem = Lg & 4095, d = rem >> 7, cc = rem & 127;
      int cp = cc ^ ((d & 7) << 2);
      u16x4 v = *(const u16x4*)(smem + hhl * 4096 + d * 128 + cp);
      int hg = hbase + hhl;
      *(u16x4*)(V3b + ((size_t)hg * 8192 + r * 32 + d) * 384 + cb + cc) = v;
    }
  }
}

// ---------------- k_qk_mma: R15 verbatim (128x128 tiles, split-K x4, 432 blocks) ----------------
__global__ __launch_bounds__(256, 4) void k_qk_mma(
    const unsigned short* __restrict__ Q3b, const unsigned short* __restrict__ K3b,
    float* __restrict__ QKf0, float* __restrict__ QKf1,
    float* __restrict__ QKf2, float* __restrict__ QKf3) {
  __shared__ unsigned short sA[2 * 4096], sB[2 * 4096];  // 16KB each
  int Dd = blockIdx.x;                       // 432 blocks; /8 = 54 -> bijective
  int L = (Dd & 7) * 54 + (Dd >> 3);
  int kh = L / 108, rem = L - kh * 108;
  int h = rem / 9, r2 = rem - h * 9, bi = r2 / 3, bj = r2 - bi * 3;
  int i0 = bi * 128, j0 = bj * 128;
  int wave = threadIdx.x >> 6, wr = wave >> 1, wc = wave & 1;
  int lane = threadIdx.x & 63, id16 = lane & 15, g = lane >> 4;
  f32x4 acc[4][4];
#pragma unroll
  for (int mi = 0; mi < 4; ++mi)
#pragma unroll
    for (int ni = 0; ni < 4; ++ni) acc[mi][ni] = (f32x4){0.f, 0.f, 0.f, 0.f};

  for (int it = 0; it < 32; ++it) {
    int r = kh * 64 + it * 2;
#pragma unroll
    for (int rr = 0; rr < 2; ++rr) {
      stageT<128, 4, 3, 1>(Q3b + (((size_t)h * 256 + r + rr) * 384 + i0) * 32, 32,
                           sA + rr * 4096);
      stageT<128, 4, 3, 1>(K3b + (((size_t)h * 256 + r + rr) * 384 + j0) * 32, 32,
                           sB + rr * 4096);
    }
    __syncthreads();
#pragma unroll
    for (int rr = 0; rr < 2; ++rr) {
      short8 Af[4], Bf[4];
#pragma unroll
      for (int mi = 0; mi < 4; ++mi)
        Af[mi] = fragLd<3, 1>(sA + rr * 4096, wr * 64 + mi * 16 + id16, g, 32);
#pragma unroll
      for (int ni = 0; ni < 4; ++ni)
        Bf[ni] = fragLd<3, 1>(sB + rr * 4096, wc * 64 + ni * 16 + id16, g, 32);
#pragma unroll
      for (int mi = 0; mi < 4; ++mi)
#pragma unroll
        for (int ni = 0; ni < 4; ++ni)
          acc[mi][ni] = __builtin_amdgcn_mfma_f32_16x16x32_bf16(Af[mi], Bf[ni],
                                                                acc[mi][ni], 0, 0, 0);
    }
    __syncthreads();
  }
  int l4 = (lane >> 4) * 4;
  float* dst = (kh == 0) ? QKf0 : (kh == 1) ? QKf1 : (kh == 2) ? QKf2 : QKf3;
#pragma unroll
  for (int mi = 0; mi < 4; ++mi)
#pragma unroll
    for (int ni = 0; ni < 4; ++ni) {
      int ii = i0 + wr * 64 + mi * 16 + l4;
      int j = j0 + wc * 64 + ni * 16 + id16;
      f32x4 a = acc[mi][ni];
#pragma unroll
      for (int reg = 0; reg < 4; ++reg)
        dst[((size_t)h * 384 + ii + reg) * 384 + j] = a[reg];
    }
}

// ---------------- k_softmax_j: sum 4 split-K partials, softmax, emit bf16 ----------------
__global__ void k_softmax_j(const int* __restrict__ res_mask, const float* __restrict__ QKf0,
                            const float* __restrict__ QKf1, const float* __restrict__ QKf2,
                            const float* __restrict__ QKf3,
                            unsigned short* __restrict__ attnb) {
  int i = blockIdx.x, h = blockIdx.y, t = threadIdx.x;
  int lane = t & 63, wid = t >> 6;
  size_t base = ((size_t)h * C_ + i) * C_;
  float v = (QKf0[base + t] + QKf1[base + t]) + (QKf2[base + t] + QKf3[base + t]);
  if ((res_mask[i] * res_mask[t]) == 0) v = NEGF;
  __shared__ float red[6];
  float m = waveRedMax(v);
  if (lane == 0) red[wid] = m;
  __syncthreads();
  float mx = red[0];
#pragma unroll
  for (int w = 1; w < 6; ++w) mx = fmaxf(mx, red[w]);
  __syncthreads();
  float e = expf(v - mx);
  float s = waveRedSum(e);
  if (lane == 0) red[wid] = s;
  __syncthreads();
  float sum = 0.f;
#pragma unroll
  for (int w = 0; w < 6; ++w) sum += red[w];
  attnb[base + t] = bf16h(e / sum);
}

// ---------------- k_out_mma: R15 verbatim (BK=64 single-buffer, f32 LDS epilogue) ----------------
__global__ __launch_bounds__(256, 4) void k_out_mma(
    const unsigned short* __restrict__ attnb, const unsigned short* __restrict__ V3b,
    float* __restrict__ out) {
  __shared__ __align__(16) unsigned short smem[2 * 128 * 64];  // 32KB; epi reuse as f32
  unsigned short* sA = smem;
  unsigned short* sB = smem + 128 * 64;
  int Dd = blockIdx.x;                        // 2304 blocks; /8 = 288 -> bijective
  int L = (Dd & 7) * 288 + (Dd >> 3);
  int bn = L % 64, bm = (L / 64) % 3, h = L / 192;
  int n0 = bn * 128, m0 = bm * 128;
  int wave = threadIdx.x >> 6, wr = wave >> 1, wc = wave & 1;
  int lane = threadIdx.x & 63, id16 = lane & 15, g = lane >> 4;
  f32x4 acc[4][4];
#pragma unroll
  for (int mi = 0; mi < 4; ++mi)
#pragma unroll
    for (int ni = 0; ni < 4; ++ni) acc[mi][ni] = (f32x4){0.f, 0.f, 0.f, 0.f};
  const unsigned short* Ab = attnb + (size_t)h * 384 * 384 + (size_t)m0 * 384;
  const unsigned short* Bb = V3b + (size_t)h * 8192 * 384 + (size_t)n0 * 384;

  for (int it = 0; it < 6; ++it) {
    stageT<128, 8, 7, 0>(Ab + it * 64, 384, sA);
    stageT<128, 8, 7, 0>(Bb + it * 64, 384, sB);
    __syncthreads();
    short8 Af[4][2], Bf[4][2];
#pragma unroll
    for (int mi = 0; mi < 4; ++mi) {
      int row = wr * 64 + mi * 16 + id16;
#pragma unroll
      for (int kk = 0; kk < 2; ++kk) Af[mi][kk] = fragLd<7, 0>(sA, row, kk * 4 + g, 64);
    }
#pragma unroll
    for (int ni = 0; ni < 4; ++ni) {
      int col = wc * 64 + ni * 16 + id16;
#pragma unroll
      for (int kk = 0; kk < 2; ++kk) Bf[ni][kk] = fragLd<7, 0>(sB, col, kk * 4 + g, 64);
    }
#pragma unroll
    for (int kk = 0; kk < 2; ++kk)
#pragma unroll
      for (int mi = 0; mi < 4; ++mi)
#pragma unroll
        for (int ni = 0; ni < 4; ++ni)
          acc[mi][ni] = __builtin_amdgcn_mfma_f32_16x16x32_bf16(Af[mi][kk], Bf[ni][kk],
                                                                acc[mi][ni], 0, 0, 0);
    __syncthreads();
  }

  int l4 = (lane >> 4) * 4;
  float* smf = (float*)smem;
#pragma unroll
  for (int p = 0; p < 2; ++p) {
#pragma unroll
    for (int mi = 0; mi < 4; ++mi) {
      int iL = wr * 64 + mi * 16 + l4;
#pragma unroll
      for (int nq = 0; nq < 2; ++nq) {
        int ni = 2 * p + nq;
        int d = nq * 16 + id16;
        f32x4 a = acc[mi][ni];
#pragma unroll
        for (int reg = 0; reg < 4; ++reg)
          smf[wc * 4096 + (iL + reg) * 32 + d] = a[reg];
      }
    }
    __syncthreads();
#pragma unroll
    for (int seg = 0; seg < 8; ++seg) {
      int o = seg * 1024 + threadIdx.x * 4;
      int plane = o >> 12, rest = o & 4095;
      int iL = rest >> 5, d = rest & 31;
      int rg = (n0 >> 5) + plane * 2 + p;
      *(float4*)&out[(((size_t)rg * 384 + m0 + iL) * 12 + h) * 32 + d] =
          *(const float4*)&smf[o];
    }
    __syncthreads();
  }
}

extern "C" void kernel_launch(void* const* d_in, const int* in_sizes, int n_in,
                              void* d_out, int out_size, void* d_ws, size_t ws_size,
                              hipStream_t stream) {
  const float* x = (const float*)d_in[0];
  const float* Wq = (const float*)d_in[1];
  const float* Wk = (const float*)d_in[2];
  const float* Wv = (const float*)d_in[3];
  const float* Wq_s = (const float*)d_in[4];
  const float* Wk_s = (const float*)d_in[5];
  const int* res_mask = (const int*)d_in[6];
  const int* seq_mask = (const int*)d_in[7];
  float* ws = (float*)d_ws;
  char* wsb = (char*)d_ws;
  float* out = (float*)d_out;

  float* swT          = ws + o_logits;
  unsigned short* Wtb = (unsigned short*)(wsb + o_attn * 4);
  float* QKf0         = ws + o_attn;
  unsigned short* Q3b = (unsigned short*)(wsb + ob_q3b);
  unsigned short* K3b = (unsigned short*)(wsb + ob_k3b);
  unsigned short* V3b = (unsigned short*)(wsb + ob_v3b);
  unsigned short* xb  = (unsigned short*)(wsb + ob_xb);
  unsigned short* attnb = Q3b;
  float* QKf1 = (float*)(wsb + ob_xb);
  float* QKf2 = (float*)(wsb + ob_xb + QKSZ);
  float* QKf3 = (float*)(wsb + ob_xb + 2 * QKSZ);

  hipLaunchKernelGGL(k_prep, dim3(7296), dim3(384), 0, stream, x, Wq, Wk, Wv, xb, Wtb);
  hipLaunchKernelGGL(k_logits_sm, dim3(C_), dim3(256), 0, stream, x, xb, Wq_s, Wk_s,
                     seq_mask, swT);
  hipLaunchKernelGGL(k_proj_all, dim3(6912), dim3(256), 0, stream, xb, Wtb, swT,
                     Q3b, K3b, V3b);
  hipLaunchKernelGGL(k_qk_mma, dim3(432), dim3(256), 0, stream, Q3b, K3b,
                     QKf0, QKf1, QKf2, QKf3);
  hipLaunchKernelGGL(k_softmax_j, dim3(C_, H_), dim3(C_), 0, stream, res_mask,
                     QKf0, QKf1, QKf2, QKf3, attnb);
  hipLaunchKernelGGL(k_out_mma, dim3(2304), dim3(256), 0, stream, attnb, V3b, out);
}

// Round 18
// 357.194 us; speedup vs baseline: 1.0931x; 1.0036x over previous
//
#include <hip/hip_runtime.h>
#include <math.h>
#include <stdint.h>

#define DEV_INLINE __device__ __forceinline__

constexpr int R_ = 256, C_ = 384, E_ = 384, H_ = 12, D_ = 32;
constexpr float NEGF = -3.402823466e38f;

typedef __attribute__((ext_vector_type(4))) float f32x4;
typedef __attribute__((ext_vector_type(8))) short short8;
typedef __attribute__((ext_vector_type(4))) unsigned short u16x4;

// ---------------- workspace layout ----------------
constexpr size_t o_logits = (size_t)C_ * E_ + (size_t)C_ * H_ * E_;  // swT f32 [12][256][384]
constexpr size_t o_sw     = o_logits + (size_t)C_ * H_ * R_;
constexpr size_t o_attn   = o_sw + (size_t)C_ * H_ * R_;             // Wtb overlay (pre-qk)
constexpr size_t o_q3     = o_attn + (size_t)H_ * C_ * C_;
constexpr size_t SZBIG  = 75497472;                  // bytes per big region
constexpr size_t ob_q3b = o_q3 * 4;                  // (attnb overlays after qk)
constexpr size_t ob_k3b = ob_q3b + SZBIG;
constexpr size_t ob_v3b = ob_k3b + SZBIG;
constexpr size_t ob_xb  = ob_v3b + SZBIG;            // ends 326,172,672; partials overlay after proj
constexpr size_t PSZ    = 3538944;                   // H*C*C*2 bytes (bf16 partial)

// ---------------- helpers ----------------
DEV_INLINE unsigned short bf16h(float x) {
  unsigned int u = __builtin_bit_cast(unsigned int, x);
  unsigned int r = (u + 0x7FFFu + ((u >> 16) & 1u)) >> 16;
  return (unsigned short)r;
}
DEV_INLINE float b2f(unsigned short u) {
  return __builtin_bit_cast(float, ((unsigned int)u) << 16);
}
DEV_INLINE float waveRedMax(float v) {
#pragma unroll
  for (int o = 32; o > 0; o >>= 1) v = fmaxf(v, __shfl_down(v, o));
  return v;
}
DEV_INLINE float waveRedSum(float v) {
#pragma unroll
  for (int o = 32; o > 0; o >>= 1) v += __shfl_down(v, o);
  return v;
}

// ---------------- async global->LDS staging (linear LDS + swizzled source) ----------------
DEV_INLINE void gll16(const void* g, void* l) {
  __builtin_amdgcn_global_load_lds(
      reinterpret_cast<__attribute__((address_space(1))) void*>(
          reinterpret_cast<uintptr_t>(g)),
      reinterpret_cast<__attribute__((address_space(3))) void*>(
          reinterpret_cast<uintptr_t>(l)),
      16, 0, 0);
}

template <int ROWS, int UPR, int MASK, int SHIFT>
DEV_INLINE void stageT(const unsigned short* __restrict__ g, int lda,
                       unsigned short* l) {
  int t = threadIdx.x, w = t >> 6, lane = t & 63;
  constexpr int NI = (ROWS * UPR) / 64;
  constexpr int PW = NI / 4;
#pragma unroll
  for (int j = 0; j < PW; ++j) {
    int u0 = (w * PW + j) * 64;
    int u = u0 + lane;
    int row = u / UPR, qp = u % UPR;
    int q = qp ^ ((row >> SHIFT) & MASK);
    gll16(g + (size_t)row * lda + q * 8, l + (size_t)u0 * 8);
  }
}

template <int MASK, int SHIFT>
DEV_INLINE short8 fragLd(const unsigned short* base, int row, int q, int rowShorts) {
  int qp = q ^ ((row >> SHIFT) & MASK);
  return *(const short8*)(base + row * rowShorts + qp * 8);
}

// ================= k_prep: cvt_x + cvt_w fused =================
__global__ void k_prep(const float* __restrict__ x, const float* __restrict__ Wq,
                       const float* __restrict__ Wk, const float* __restrict__ Wv,
                       unsigned short* __restrict__ xb, unsigned short* __restrict__ Wtb) {
  int bid = blockIdx.x, t = threadIdx.x;
  if (bid < 6144) {
    size_t i = ((size_t)bid * 384 + t) * 16;
    unsigned short h[16];
#pragma unroll
    for (int j = 0; j < 4; ++j) {
      float4 f = *(const float4*)&x[i + j * 4];
      h[j * 4 + 0] = bf16h(f.x);
      h[j * 4 + 1] = bf16h(f.y);
      h[j * 4 + 2] = bf16h(f.z);
      h[j * 4 + 3] = bf16h(f.w);
    }
    *(short8*)&xb[i] = *(const short8*)&h[0];
    *(short8*)&xb[i + 8] = *(const short8*)&h[8];
  } else {
    int n = bid - 6144;
    const float* W;
    int col;
    if (n < 384)      { W = Wq; col = n; }
    else if (n < 768) { W = Wk; col = n - 384; }
    else              { W = Wv; col = n - 768; }
    Wtb[(size_t)n * 384 + t] = bf16h(W[(size_t)t * 384 + col]);
  }
}

// ---------------- fused qs + p + logits + softmax_r -> swT[h][r][c] ----------------
__global__ __launch_bounds__(256) void k_logits_sm(
    const float* __restrict__ x, const unsigned short* __restrict__ xb,
    const float* __restrict__ Wq_s, const float* __restrict__ Wk_s,
    const int* __restrict__ seq_mask, float* __restrict__ swT) {
  int c = blockIdx.x, t = threadIdx.x;
  __shared__ float xq[384], qs_l[384];
  __shared__ unsigned short pB[16 * 392];
  __shared__ unsigned short sA[256 * 32];
  __shared__ float lg[12 * 256];
  __shared__ float red[4];
  int w = t >> 6, lane = t & 63, id16 = lane & 15, g = lane >> 4;

  for (int k = t; k < 384; k += 256) xq[k] = x[(size_t)c * 384 + k];
  __syncthreads();
  for (int e = t; e < 384; e += 256) {
    float s = 0.f;
    for (int k = 0; k < 384; ++k) s += xq[k] * Wq_s[(size_t)k * 384 + e];
    qs_l[e] = s * 0.17677669529663687f;
  }
  __syncthreads();
  for (int idx = t; idx < 4608; idx += 256) {
    int h = idx / 384, kk = idx - h * 384;
    const float* wrow = &Wk_s[(size_t)kk * 384 + h * 32];
    const float* qv = &qs_l[h * 32];
    float s = 0.f;
#pragma unroll
    for (int d = 0; d < 32; d += 4) {
      float4 wv = *(const float4*)&wrow[d];
      s += wv.x * qv[d] + wv.y * qv[d + 1] + wv.z * qv[d + 2] + wv.w * qv[d + 3];
    }
    pB[h * 392 + kk] = bf16h(s);
  }
  for (int i = t + 12 * 392; i < 16 * 392; i += 256) pB[i] = 0;
  __syncthreads();

  f32x4 acc[4];
#pragma unroll
  for (int mi = 0; mi < 4; ++mi) acc[mi] = (f32x4){0.f, 0.f, 0.f, 0.f};
  for (int k0 = 0; k0 < 384; k0 += 32) {
    stageT<256, 4, 3, 0>(xb + (size_t)c * 384 + k0, 384 * 384, sA);
    __syncthreads();
    short8 Bf = *(const short8*)(pB + id16 * 392 + k0 + g * 8);
#pragma unroll
    for (int mi = 0; mi < 4; ++mi) {
      short8 Af = fragLd<3, 0>(sA, w * 64 + mi * 16 + id16, g, 32);
      acc[mi] = __builtin_amdgcn_mfma_f32_16x16x32_bf16(Af, Bf, acc[mi], 0, 0, 0);
    }
    __syncthreads();
  }
  int l4 = (lane >> 4) * 4;
#pragma unroll
  for (int mi = 0; mi < 4; ++mi) {
    if (id16 < 12) {
      f32x4 a = acc[mi];
#pragma unroll
      for (int reg = 0; reg < 4; ++reg)
        lg[id16 * 256 + w * 64 + mi * 16 + l4 + reg] = a[reg];
    }
  }
  __syncthreads();
  int wid = t >> 6;
  const float scal = 0.17677669529663687f / sqrtf((float)C_);
  bool masked = (seq_mask[t] == 0);
  for (int h = 0; h < 12; ++h) {
    float v = masked ? NEGF : lg[h * 256 + t];
    float m = waveRedMax(v);
    if ((t & 63) == 0) red[wid] = m;
    __syncthreads();
    float mx = fmaxf(fmaxf(red[0], red[1]), fmaxf(red[2], red[3]));
    __syncthreads();
    float e = expf(v - mx);
    float s = waveRedSum(e);
    if ((t & 63) == 0) red[wid] = s;
    __syncthreads();
    float sum = red[0] + red[1] + red[2] + red[3];
    swT[((size_t)h * 256 + t) * 384 + c] = e / sum * scal;
    __syncthreads();
  }
}

// ---------------- k_proj_all (R17-verbatim) ----------------
__global__ __launch_bounds__(256, 4) void k_proj_all(
    const unsigned short* __restrict__ xb, const unsigned short* __restrict__ Wtb,
    const float* __restrict__ swT, unsigned short* __restrict__ Q3b,
    unsigned short* __restrict__ K3b, unsigned short* __restrict__ V3b) {
  __shared__ __align__(16) unsigned short smem[2 * 128 * 64];
  unsigned short* sA = smem;
  unsigned short* sB = smem + 128 * 64;
  int Dd = blockIdx.x;
  int L = (Dd & 7) * 864 + (Dd >> 3);
  int bm = L / 9, bn = L - bm * 9;
  int n0 = bn * 128, m0 = bm * 128;
  int wave = threadIdx.x >> 6, wr = wave >> 1, wc = wave & 1;
  int lane = threadIdx.x & 63, id16 = lane & 15, g = lane >> 4;
  f32x4 acc[4][4];
#pragma unroll
  for (int mi = 0; mi < 4; ++mi)
#pragma unroll
    for (int ni = 0; ni < 4; ++ni) acc[mi][ni] = (f32x4){0.f, 0.f, 0.f, 0.f};

  for (int it = 0; it < 6; ++it) {
    stageT<128, 8, 7, 0>(xb + (size_t)m0 * 384 + it * 64, 384, sA);
    stageT<128, 8, 7, 0>(Wtb + (size_t)n0 * 384 + it * 64, 384, sB);
    __syncthreads();
    short8 Af[4][2], Bf[4][2];
#pragma unroll
    for (int mi = 0; mi < 4; ++mi) {
      int row = wr * 64 + mi * 16 + id16;
#pragma unroll
      for (int kk = 0; kk < 2; ++kk) Af[mi][kk] = fragLd<7, 0>(sA, row, kk * 4 + g, 64);
    }
#pragma unroll
    for (int ni = 0; ni < 4; ++ni) {
      int col = wc * 64 + ni * 16 + id16;
#pragma unroll
      for (int kk = 0; kk < 2; ++kk) Bf[ni][kk] = fragLd<7, 0>(sB, col, kk * 4 + g, 64);
    }
#pragma unroll
    for (int kk = 0; kk < 2; ++kk)
#pragma unroll
      for (int mi = 0; mi < 4; ++mi)
#pragma unroll
        for (int ni = 0; ni < 4; ++ni)
          acc[mi][ni] = __builtin_amdgcn_mfma_f32_16x16x32_bf16(Af[mi][kk], Bf[ni][kk],
                                                                acc[mi][ni], 0, 0, 0);
    __syncthreads();
  }

  int l4 = (lane >> 4) * 4;
  int r = bm / 3, cb = (bm % 3) * 128;
  if (bn < 6) {
    bool isQ = bn < 3;
    int hbase = isQ ? bn * 4 : (bn - 3) * 4;
#pragma unroll
    for (int mi = 0; mi < 4; ++mi) {
      int clBase = wr * 64 + mi * 16 + l4;
#pragma unroll
      for (int ni = 0; ni < 4; ++ni) {
        int nl = wc * 64 + ni * 16 + id16;
        int hhl = nl >> 5, d = nl & 31;
        f32x4 a = acc[mi][ni];
        if (isQ) {
          float4 sv =
              *(const float4*)&swT[((size_t)(hbase + hhl) * 256 + r) * 384 + cb + clBase];
          a[0] *= sv.x; a[1] *= sv.y; a[2] *= sv.z; a[3] *= sv.w;
        }
#pragma unroll
        for (int reg = 0; reg < 4; ++reg)
          smem[hhl * 4096 + (clBase + reg) * 32 + d] = bf16h(a[reg]);
      }
    }
    __syncthreads();
    unsigned short* dst = isQ ? Q3b : K3b;
#pragma unroll
    for (int seg = 0; seg < 8; ++seg) {
      int off = seg * 2048 + threadIdx.x * 8;
      int hhl = off >> 12, inner = off & 4095;
      int hg = hbase + hhl;
      *(short8*)(dst + (((size_t)hg * 256 + r) * 384 + cb) * 32 + inner) =
          *(const short8*)(smem + off);
    }
  } else {
    int hbase = (bn - 6) * 4;
#pragma unroll
    for (int mi = 0; mi < 4; ++mi) {
      int clBase = wr * 64 + mi * 16 + l4;
#pragma unroll
      for (int ni = 0; ni < 4; ++ni) {
        int nl = wc * 64 + ni * 16 + id16;
        int hhl = nl >> 5, d = nl & 31;
        int cg = clBase ^ ((d & 7) << 2);
        f32x4 a = acc[mi][ni];
        u16x4 hv;
#pragma unroll
        for (int reg = 0; reg < 4; ++reg) hv[reg] = bf16h(a[reg]);
        *(u16x4*)(smem + hhl * 4096 + d * 128 + cg) = hv;
      }
    }
    __syncthreads();
#pragma unroll
    for (int seg = 0; seg < 16; ++seg) {
      int Lg = seg * 1024 + threadIdx.x * 4;
      int hhl = Lg >> 12, rem = Lg & 4095, d = rem >> 7, cc = rem & 127;
      int cp = cc ^ ((d & 7) << 2);
      u16x4 v = *(const u16x4*)(smem + hhl * 4096 + d * 128 + cp);
      int hg = hbase + hhl;
      *(u16x4*)(V3b + ((size_t)hg * 8192 + r * 32 + d) * 384 + cb + cc) = v;
    }
  }
}

// ---------------- k_qk_mma: 128x128, split-K x4, bf16 partials ----------------
__global__ __launch_bounds__(256, 4) void k_qk_mma(
    const unsigned short* __restrict__ Q3b, const unsigned short* __restrict__ K3b,
    unsigned short* __restrict__ P0, unsigned short* __restrict__ P1,
    unsigned short* __restrict__ P2, unsigned short* __restrict__ P3) {
  __shared__ unsigned short sA[2 * 4096], sB[2 * 4096];
  int Dd = blockIdx.x;                       // 432 blocks; /8 = 54 -> bijective
  int L = (Dd & 7) * 54 + (Dd >> 3);
  int kh = L / 108, rem = L - kh * 108;
  int h = rem / 9, r2 = rem - h * 9, bi = r2 / 3, bj = r2 - bi * 3;
  int i0 = bi * 128, j0 = bj * 128;
  int wave = threadIdx.x >> 6, wr = wave >> 1, wc = wave & 1;
  int lane = threadIdx.x & 63, id16 = lane & 15, g = lane >> 4;
  f32x4 acc[4][4];
#pragma unroll
  for (int mi = 0; mi < 4; ++mi)
#pragma unroll
    for (int ni = 0; ni < 4; ++ni) acc[mi][ni] = (f32x4){0.f, 0.f, 0.f, 0.f};

  for (int it = 0; it < 32; ++it) {
    int r = kh * 64 + it * 2;
#pragma unroll
    for (int rr = 0; rr < 2; ++rr) {
      stageT<128, 4, 3, 1>(Q3b + (((size_t)h * 256 + r + rr) * 384 + i0) * 32, 32,
                           sA + rr * 4096);
      stageT<128, 4, 3, 1>(K3b + (((size_t)h * 256 + r + rr) * 384 + j0) * 32, 32,
                           sB + rr * 4096);
    }
    __syncthreads();
#pragma unroll
    for (int rr = 0; rr < 2; ++rr) {
      short8 Af[4], Bf[4];
#pragma unroll
      for (int mi = 0; mi < 4; ++mi)
        Af[mi] = fragLd<3, 1>(sA + rr * 4096, wr * 64 + mi * 16 + id16, g, 32);
#pragma unroll
      for (int ni = 0; ni < 4; ++ni)
        Bf[ni] = fragLd<3, 1>(sB + rr * 4096, wc * 64 + ni * 16 + id16, g, 32);
#pragma unroll
      for (int mi = 0; mi < 4; ++mi)
#pragma unroll
        for (int ni = 0; ni < 4; ++ni)
          acc[mi][ni] = __builtin_amdgcn_mfma_f32_16x16x32_bf16(Af[mi], Bf[ni],
                                                                acc[mi][ni], 0, 0, 0);
    }
    __syncthreads();
  }
  int l4 = (lane >> 4) * 4;
  unsigned short* dst = (kh == 0) ? P0 : (kh == 1) ? P1 : (kh == 2) ? P2 : P3;
#pragma unroll
  for (int mi = 0; mi < 4; ++mi)
#pragma unroll
    for (int ni = 0; ni < 4; ++ni) {
      int ii = i0 + wr * 64 + mi * 16 + l4;
      int j = j0 + wc * 64 + ni * 16 + id16;
      f32x4 a = acc[mi][ni];
#pragma unroll
      for (int reg = 0; reg < 4; ++reg)
        dst[((size_t)h * 384 + ii + reg) * 384 + j] = bf16h(a[reg]);
    }
}

// ---------------- k_softmax_j: sum bf16 partials, softmax, emit bf16 ----------------
__global__ void k_softmax_j(const int* __restrict__ res_mask,
                            const unsigned short* __restrict__ P0,
                            const unsigned short* __restrict__ P1,
                            const unsigned short* __restrict__ P2,
                            const unsigned short* __restrict__ P3,
                            unsigned short* __restrict__ attnb) {
  int i = blockIdx.x, h = blockIdx.y, t = threadIdx.x;
  int lane = t & 63, wid = t >> 6;
  size_t base = ((size_t)h * C_ + i) * C_;
  float v = (b2f(P0[base + t]) + b2f(P1[base + t])) +
            (b2f(P2[base + t]) + b2f(P3[base + t]));
  if ((res_mask[i] * res_mask[t]) == 0) v = NEGF;
  __shared__ float red[6];
  float m = waveRedMax(v);
  if (lane == 0) red[wid] = m;
  __syncthreads();
  float mx = red[0];
#pragma unroll
  for (int w = 1; w < 6; ++w) mx = fmaxf(mx, red[w]);
  __syncthreads();
  float e = expf(v - mx);
  float s = waveRedSum(e);
  if (lane == 0) red[wid] = s;
  __syncthreads();
  float sum = 0.f;
#pragma unroll
  for (int w = 0; w < 6; ++w) sum += red[w];
  attnb[base + t] = bf16h(e / sum);
}

// ---------------- k_out_mma: M=384(all i) x N=64 rd; V read once ----------------
__global__ __launch_bounds__(256, 3) void k_out_mma(
    const unsigned short* __restrict__ attnb, const unsigned short* __restrict__ V3b,
    float* __restrict__ out) {
  __shared__ __align__(16) unsigned short smem[16384];  // 32KB; sA|sB then f32 epi
  unsigned short* sA = smem;            // 384 x 32 = 12288 shorts
  unsigned short* sB = smem + 12288;    // 64 x 32 = 2048 shorts
  int Dd = blockIdx.x;                  // 1536 blocks; /8 = 192 -> bijective
  int L = (Dd & 7) * 192 + (Dd >> 3);
  int h = L >> 7, rdt = L & 127;        // h-major: attn tile L2-resident
  int w = threadIdx.x >> 6;
  int lane = threadIdx.x & 63, id16 = lane & 15, g = lane >> 4;
  f32x4 acc[6][4];
#pragma unroll
  for (int mi = 0; mi < 6; ++mi)
#pragma unroll
    for (int nf = 0; nf < 4; ++nf) acc[mi][nf] = (f32x4){0.f, 0.f, 0.f, 0.f};
  const unsigned short* Ab = attnb + (size_t)h * 147456;
  const unsigned short* Bb = V3b + (size_t)h * 8192 * 384 + (size_t)(rdt * 64) * 384;

  for (int it = 0; it < 12; ++it) {
    stageT<384, 4, 3, 1>(Ab + it * 32, 384, sA);
    stageT<64, 4, 3, 1>(Bb + it * 32, 384, sB);
    __syncthreads();
    short8 Af[6], Bf[4];
#pragma unroll
    for (int mi = 0; mi < 6; ++mi)
      Af[mi] = fragLd<3, 1>(sA, w * 96 + mi * 16 + id16, g, 32);
#pragma unroll
    for (int nf = 0; nf < 4; ++nf)
      Bf[nf] = fragLd<3, 1>(sB, nf * 16 + id16, g, 32);
#pragma unroll
    for (int mi = 0; mi < 6; ++mi)
#pragma unroll
      for (int nf = 0; nf < 4; ++nf)
        acc[mi][nf] = __builtin_amdgcn_mfma_f32_16x16x32_bf16(Af[mi], Bf[nf],
                                                              acc[mi][nf], 0, 0, 0);
    __syncthreads();
  }

  // Epilogue: 3 passes of 128 i; stage [i 128][rd 64] f32 (32KB), write float4 runs.
  int l4 = (lane >> 4) * 4;
  float* smf = (float*)smem;
#pragma unroll
  for (int p = 0; p < 3; ++p) {
#pragma unroll
    for (int mi = 0; mi < 6; ++mi) {
      int rb = w * 96 + mi * 16;
      if ((rb >> 7) != p) continue;
      int ibase = (rb & 127) + l4;
#pragma unroll
      for (int nf = 0; nf < 4; ++nf) {
        int rdl = nf * 16 + id16;
        f32x4 a = acc[mi][nf];
#pragma unroll
        for (int reg = 0; reg < 4; ++reg)
          smf[(ibase + reg) * 64 + rdl] = a[reg];
      }
    }
    __syncthreads();
#pragma unroll
    for (int seg = 0; seg < 8; ++seg) {
      int o = seg * 1024 + threadIdx.x * 4;
      int il = o >> 6, rdl = o & 63;
      int rg = rdt * 2 + (rdl >> 5), d = rdl & 31;
      int i = p * 128 + il;
      *(float4*)&out[(((size_t)rg * 384 + i) * 12 + h) * 32 + d] =
          *(const float4*)&smf[o];
    }
    __syncthreads();
  }
}

extern "C" void kernel_launch(void* const* d_in, const int* in_sizes, int n_in,
                              void* d_out, int out_size, void* d_ws, size_t ws_size,
                              hipStream_t stream) {
  const float* x = (const float*)d_in[0];
  const float* Wq = (const float*)d_in[1];
  const float* Wk = (const float*)d_in[2];
  const float* Wv = (const float*)d_in[3];
  const float* Wq_s = (const float*)d_in[4];
  const float* Wk_s = (const float*)d_in[5];
  const int* res_mask = (const int*)d_in[6];
  const int* seq_mask = (const int*)d_in[7];
  float* ws = (float*)d_ws;
  char* wsb = (char*)d_ws;
  float* out = (float*)d_out;

  float* swT          = ws + o_logits;
  unsigned short* Wtb = (unsigned short*)(wsb + o_attn * 4);
  unsigned short* Q3b = (unsigned short*)(wsb + ob_q3b);
  unsigned short* K3b = (unsigned short*)(wsb + ob_k3b);
  unsigned short* V3b = (unsigned short*)(wsb + ob_v3b);
  unsigned short* xb  = (unsigned short*)(wsb + ob_xb);
  unsigned short* attnb = Q3b;  // overlays Q3b (dead after qk)
  unsigned short* P0 = (unsigned short*)(wsb + ob_xb);            // overlay xb (dead after proj)
  unsigned short* P1 = (unsigned short*)(wsb + ob_xb + PSZ);
  unsigned short* P2 = (unsigned short*)(wsb + ob_xb + 2 * PSZ);
  unsigned short* P3 = (unsigned short*)(wsb + ob_xb + 3 * PSZ);

  hipLaunchKernelGGL(k_prep, dim3(7296), dim3(384), 0, stream, x, Wq, Wk, Wv, xb, Wtb);
  hipLaunchKernelGGL(k_logits_sm, dim3(C_), dim3(256), 0, stream, x, xb, Wq_s, Wk_s,
                     seq_mask, swT);
  hipLaunchKernelGGL(k_proj_all, dim3(6912), dim3(256), 0, stream, xb, Wtb, swT,
                     Q3b, K3b, V3b);
  hipLaunchKernelGGL(k_qk_mma, dim3(432), dim3(256), 0, stream, Q3b, K3b, P0, P1, P2, P3);
  hipLaunchKernelGGL(k_softmax_j, dim3(C_, H_), dim3(C_), 0, stream, res_mask,
                     P0, P1, P2, P3, attnb);
  hipLaunchKernelGGL(k_out_mma, dim3(1536), dim3(256), 0, stream, attnb, V3b, out);
}